// Round 14
// baseline (80.398 us; speedup 1.0000x reference)
//
#include <hip/hip_runtime.h>

// LinearAttention: b=2, c=64, N=48^3=110592, HEADS=4, DIM_HEAD=32.
//
//   y[o,n] = sum_c Wf[b][o,c] x[c,n] + b_out[o]
//   Wf[b]  = w_out · T,  T[h,e,c] = sum_d ctx[h,d,e]·Wq[h*32+d,c]
//   ctx[h,d,e] = (sum_n exp(k[d,n]) v[e,n]) / (sum_n exp(k[d,n]))
// exp without max-subtraction: k ~ N(0,0.16) (verified rounds 2-13).
//
// Round-14: the fused kv was stuck at ~40us (~2.4TB/s): its phase-A global
// xT stores force the compiler's s_waitcnt vmcnt(0) before each s_barrier,
// draining the issue-early prefetch loads -> every iter serializes on HBM
// latency. Fix: BARRIER-FREE kv. Separate streaming transpose (x->xT, pure
// BW) + kv reading A-frags directly from xT (dwordx4; L3-resident 28MB),
// PV per-wave-private LDS (20.5KB/block, no __syncthreads at all).

#define C_IN 64

typedef __attribute__((ext_vector_type(8))) short short8;
typedef __attribute__((ext_vector_type(4))) float f32x4;

static __device__ __forceinline__ unsigned short f2bf(float f) {
    union { float f; unsigned u; } x; x.f = f;
    return (unsigned short)((x.u + 0x7fffu + ((x.u >> 16) & 1u)) >> 16); // RNE
}

// ---------------------------------------------------------------------------
// Kernel 0: x[c][n] f32 -> xT[n][c] bf16 (rows of 64 bf16 = 128B). Streaming.
// ---------------------------------------------------------------------------
__global__ __launch_bounds__(256)
void transpose_kernel(const float* __restrict__ x,
                      unsigned short* __restrict__ xT,
                      int N, int bbase)
{
    __shared__ float Xs[64][65];
    const int b  = blockIdx.y + bbase;
    const int t  = threadIdx.x;
    const int n0 = blockIdx.x * 64;

    const float* xb = x + (size_t)b * C_IN * N;
    #pragma unroll
    for (int i = 0; i < 4; ++i) {
        int slot = i * 256 + t;
        int c = slot >> 4, nq = slot & 15;
        float4 v = *(const float4*)(xb + (size_t)c * N + n0 + nq * 4);
        Xs[c][nq * 4 + 0] = v.x; Xs[c][nq * 4 + 1] = v.y;
        Xs[c][nq * 4 + 2] = v.z; Xs[c][nq * 4 + 3] = v.w;
    }
    __syncthreads();

    const int n = t >> 2, q = t & 3;
    unsigned out[8];
    #pragma unroll
    for (int i = 0; i < 8; ++i) {
        float lo = Xs[q * 16 + 2 * i][n], hi = Xs[q * 16 + 2 * i + 1][n];
        out[i] = (unsigned)f2bf(lo) | ((unsigned)f2bf(hi) << 16);
    }
    unsigned short* dst = xT + ((size_t)blockIdx.y * N + n0 + n) * 64 + q * 16;
    *(uint4*)(dst)     = *(uint4*)&out[0];
    *(uint4*)(dst + 8) = *(uint4*)&out[4];
}

// ---------------------------------------------------------------------------
// Kernel 1: K/V + exp + ctx via MFMA. BARRIER-FREE: wave = head, A-frags
// straight from xT (dwordx4, L3-hot), PV per-wave-private LDS, MFMA-2 over
// two 32-n halves (round-12/13 verified layout).
// Output: part[(b*nblk+bx)*4224]: [0..4095]=ctx, [4096..4223]=S.
// ---------------------------------------------------------------------------
__global__ __launch_bounds__(256, 2)
void kv_ctx_mfma(const unsigned short* __restrict__ xT,
                 const float* __restrict__ w_qkv,
                 float* __restrict__ part,
                 int N, int nblk, int bbase)
{
    __shared__ __align__(16) char PVs[4 * 2 * 32 * 80];    // 20.5 KB (pitch 80B)

    const int by  = blockIdx.y;
    const int b   = by + bbase;
    const int bx  = blockIdx.x;
    const int t   = threadIdx.x;
    const int w   = t >> 6;         // wave id = head
    const int l   = t & 63;
    const int l15 = l & 15;
    const int lg  = l >> 4;         // 0..3

    const int n_blk = bx * 256;

    // per-wave-private PV: type p (0=P,1=V), row 0..31, col bf16 0..31
    auto pv_ptr = [&](int p, int row, int colbf) -> unsigned short* {
        return (unsigned short*)(PVs + ((size_t)((w * 2 + p) * 32 + row) * 80
                                        + colbf * 2));
    };

    // ---- weight B-frags: nt 0,1 = K rows, nt 2,3 = V rows; s = K32 slab
    short8 Wfr[4][2];
    #pragma unroll
    for (int nt = 0; nt < 4; ++nt) {
        const int row = (nt < 2) ? (128 + w * 32 + nt * 16 + l15)
                                 : (256 + w * 32 + (nt - 2) * 16 + l15);
        const float* wr = w_qkv + (size_t)row * C_IN;
        #pragma unroll
        for (int s = 0; s < 2; ++s) {
            #pragma unroll
            for (int j = 0; j < 8; ++j)
                Wfr[nt][s][j] = (short)f2bf(wr[s * 32 + lg * 8 + j]);
        }
    }

    f32x4 acc2[2][2];
    #pragma unroll
    for (int dt = 0; dt < 2; ++dt)
        #pragma unroll
        for (int et = 0; et < 2; ++et)
            acc2[dt][et] = (f32x4){0.f, 0.f, 0.f, 0.f};
    float s_loc[2] = {0.f, 0.f};

    for (int it = 0; it < 4; ++it) {
        const int nb = n_blk + it * 64;
        const unsigned short* xr = xT + ((size_t)by * N + nb) * 64;

        // ---- A-frags: one dwordx4 each (8 consecutive c at row n)
        short8 Af[4][2];
        #pragma unroll
        for (int mt = 0; mt < 4; ++mt)
            #pragma unroll
            for (int s = 0; s < 2; ++s)
                Af[mt][s] = *(const short8*)(xr + (size_t)(mt * 16 + l15) * 64
                                             + s * 32 + lg * 8);

        // ---- two 32-n halves of {MFMA-1, exp, PV pack, MFMA-2}
        #pragma unroll
        for (int h = 0; h < 2; ++h) {
            #pragma unroll
            for (int m2 = 0; m2 < 2; ++m2) {
                const int mt = h * 2 + m2;
                #pragma unroll
                for (int nt = 0; nt < 4; ++nt) {
                    f32x4 a = (f32x4){0.f, 0.f, 0.f, 0.f};
                    a = __builtin_amdgcn_mfma_f32_16x16x32_bf16(Af[mt][0], Wfr[nt][0], a, 0, 0, 0);
                    a = __builtin_amdgcn_mfma_f32_16x16x32_bf16(Af[mt][1], Wfr[nt][1], a, 0, 0, 0);
                    const int nh = m2 * 16 + lg * 4;   // n within half (0..31)
                    if (nt < 2) {
                        float e0 = __expf(a[0]), e1 = __expf(a[1]);
                        float e2 = __expf(a[2]), e3 = __expf(a[3]);
                        s_loc[nt] += (e0 + e1) + (e2 + e3);
                        uint2 p;
                        p.x = (unsigned)f2bf(e0) | ((unsigned)f2bf(e1) << 16);
                        p.y = (unsigned)f2bf(e2) | ((unsigned)f2bf(e3) << 16);
                        *(uint2*)pv_ptr(0, nt * 16 + l15, nh) = p;
                    } else {
                        uint2 p;
                        p.x = (unsigned)f2bf(a[0]) | ((unsigned)f2bf(a[1]) << 16);
                        p.y = (unsigned)f2bf(a[2]) | ((unsigned)f2bf(a[3]) << 16);
                        *(uint2*)pv_ptr(1, (nt - 2) * 16 + l15, nh) = p;
                    }
                }
            }
            // MFMA-2: ctx += P·V^T over this half's 32 n (K=32, intra-wave)
            {
                short8 A2[2], B2[2];
                #pragma unroll
                for (int dt = 0; dt < 2; ++dt)
                    A2[dt] = *(const short8*)pv_ptr(0, dt * 16 + l15, lg * 8);
                #pragma unroll
                for (int et = 0; et < 2; ++et)
                    B2[et] = *(const short8*)pv_ptr(1, et * 16 + l15, lg * 8);
                #pragma unroll
                for (int dt = 0; dt < 2; ++dt)
                    #pragma unroll
                    for (int et = 0; et < 2; ++et)
                        acc2[dt][et] = __builtin_amdgcn_mfma_f32_16x16x32_bf16(
                            A2[dt], B2[et], acc2[dt][et], 0, 0, 0);
            }
        }
    }

    // ---- plain per-block partial stores (no atomics, no zeroing)
    float* pb = part + ((size_t)b * nblk + bx) * 4224;
    #pragma unroll
    for (int dt = 0; dt < 2; ++dt)
        #pragma unroll
        for (int et = 0; et < 2; ++et)
            #pragma unroll
            for (int r = 0; r < 4; ++r)
                pb[(w * 32 + dt * 16 + lg * 4 + r) * 32 + et * 16 + l15] =
                    acc2[dt][et][r];

    #pragma unroll
    for (int nt = 0; nt < 2; ++nt) {
        float s = s_loc[nt];
        s += __shfl_xor(s, 16);
        s += __shfl_xor(s, 32);
        if (lg == 0)
            pb[4096 + w * 32 + nt * 16 + l15] = s;
    }
}

// ---------------------------------------------------------------------------
// Kernel 2: parallel partial reduce. grid (17, 16, B): block sums ~nblk/16
// chunks (coalesced over g) -> part2[b][16][4224].
// ---------------------------------------------------------------------------
__global__ __launch_bounds__(256)
void reduce_kernel(const float* __restrict__ part,
                   float* __restrict__ part2,
                   int nblk)
{
    const int b  = blockIdx.z;
    const int cy = blockIdx.y;          // 0..15
    const int g  = blockIdx.x * 256 + threadIdx.x;
    if (g >= 4224) return;

    const int cnt = (nblk + 15) / 16;
    const int c0  = cy * cnt;
    const int c1  = (c0 + cnt < nblk) ? (c0 + cnt) : nblk;

    const float* pb = part + (size_t)b * nblk * 4224 + g;
    float a0 = 0.f, a1 = 0.f, a2 = 0.f, a3 = 0.f;
    int c = c0;
    for (; c + 4 <= c1; c += 4) {
        a0 += pb[(size_t)(c + 0) * 4224];
        a1 += pb[(size_t)(c + 1) * 4224];
        a2 += pb[(size_t)(c + 2) * 4224];
        a3 += pb[(size_t)(c + 3) * 4224];
    }
    for (; c < c1; ++c) a0 += pb[(size_t)c * 4224];
    part2[((size_t)b * 16 + cy) * 4224 + g] = (a0 + a1) + (a2 + a3);
}

// ---------------------------------------------------------------------------
// Kernel 3: merge 16 replicas, normalize ctx, T = ctx·Wq, Wf = w_out·T -> bf16.
// grid (8, B): block s writes o-rows [8s, 8s+8) of Wf.
// ---------------------------------------------------------------------------
__global__ __launch_bounds__(256)
void finalize_kernel(const float* __restrict__ part2,
                     const float* __restrict__ w_qkv,
                     const float* __restrict__ w_out,
                     unsigned short* __restrict__ wf_bf)
{
    const int b = blockIdx.y;
    const int s = blockIdx.x;
    const int t = threadIdx.x;

    __shared__ float Wq[128][64];
    __shared__ float Ctx[128][36];
    __shared__ float Tt[128][68];
    __shared__ float WoS[8][128];
    __shared__ float Sinv[128];

    #pragma unroll
    for (int i = 0; i < 8; ++i) {
        int idx = i * 1024 + t * 4;
        *(float4*)&Wq[idx >> 6][idx & 63] = *(const float4*)(w_qkv + idx);
    }
    {
        int idx = t * 4;
        int o = idx >> 7, he = idx & 127;
        *(float4*)&WoS[o][he] = *(const float4*)(w_out + (size_t)(s * 8 + o) * 128 + he);
    }
    if (t < 128) {
        float ssum = 0.f;
        #pragma unroll
        for (int rep = 0; rep < 16; ++rep)
            ssum += part2[((size_t)b * 16 + rep) * 4224 + 4096 + t];
        Sinv[t] = 1.0f / ssum;
    }
    float cacc[16];
    #pragma unroll
    for (int i = 0; i < 16; ++i) cacc[i] = 0.f;
    {
        const float* cb = part2 + (size_t)b * 16 * 4224;
        for (int rep = 0; rep < 16; ++rep) {
            #pragma unroll
            for (int i = 0; i < 16; ++i)
                cacc[i] += cb[(size_t)rep * 4224 + i * 256 + t];
        }
    }
    __syncthreads();   // Sinv ready

    #pragma unroll
    for (int i = 0; i < 16; ++i) {
        int idx = i * 256 + t;          // hd*32 + e
        Ctx[idx >> 5][idx & 31] = cacc[i] * Sinv[idx >> 5];
    }
    __syncthreads();

    // ---- T: thread owns 4he x 8c tile; per d: 3 b128 reads -> 32 FMA
    {
        const int he0 = (t >> 3) * 4;
        const int c0  = (t & 7) * 8;
        const int hh  = he0 >> 5;
        const int e0  = he0 & 31;
        float acc[4][8];
        #pragma unroll
        for (int j = 0; j < 4; ++j)
            #pragma unroll
            for (int k = 0; k < 8; ++k) acc[j][k] = 0.f;

        for (int d = 0; d < 32; ++d) {
            float4 cv = *(const float4*)&Ctx[hh * 32 + d][e0];
            float4 w0 = *(const float4*)&Wq[hh * 32 + d][c0];
            float4 w1 = *(const float4*)&Wq[hh * 32 + d][c0 + 4];
            float wv[8] = {w0.x, w0.y, w0.z, w0.w, w1.x, w1.y, w1.z, w1.w};
            float cvv[4] = {cv.x, cv.y, cv.z, cv.w};
            #pragma unroll
            for (int j = 0; j < 4; ++j)
                #pragma unroll
                for (int k = 0; k < 8; ++k)
                    acc[j][k] = fmaf(cvv[j], wv[k], acc[j][k]);
        }
        #pragma unroll
        for (int j = 0; j < 4; ++j) {
            *(float4*)&Tt[he0 + j][c0]     = make_float4(acc[j][0], acc[j][1], acc[j][2], acc[j][3]);
            *(float4*)&Tt[he0 + j][c0 + 4] = make_float4(acc[j][4], acc[j][5], acc[j][6], acc[j][7]);
        }
    }
    __syncthreads();

    // ---- Wf slice: thread -> (o = 8s + t>>5, c = 2*(t&31)); 128-he dot
    {
        const int o = t >> 5;
        const int c = (t & 31) * 2;
        float a0 = 0.f, a1 = 0.f, b0 = 0.f, b1 = 0.f;
        #pragma unroll
        for (int he = 0; he < 128; he += 2) {
            float w0 = WoS[o][he], w1 = WoS[o][he + 1];
            float2 t0 = *(const float2*)&Tt[he][c];
            float2 t1 = *(const float2*)&Tt[he + 1][c];
            a0 = fmaf(w0, t0.x, a0); a1 = fmaf(w0, t0.y, a1);
            b0 = fmaf(w1, t1.x, b0); b1 = fmaf(w1, t1.y, b1);
        }
        unsigned short* dst = wf_bf + (size_t)b * 4096 + (size_t)(s * 8 + o) * 64 + c;
        dst[0] = f2bf(a0 + b0);
        dst[1] = f2bf(a1 + b1);
    }
}

// ---------------------------------------------------------------------------
// Kernel 4: y = Wf·x + b via MFMA. Wave covers 64 n x all 64 o.
// ---------------------------------------------------------------------------
__global__ __launch_bounds__(256)
void out_gemm_mfma(const unsigned short* __restrict__ xT,
                   const unsigned short* __restrict__ wf_bf,  // [B][64o][64c]
                   const float* __restrict__ b_out,
                   float* __restrict__ y,
                   int N, int bbase)
{
    const int by  = blockIdx.y;
    const int b   = by + bbase;
    const int t   = threadIdx.x;
    const int w   = t >> 6;
    const int l   = t & 63;
    const int l15 = l & 15;
    const int lg  = l >> 4;
    const int nb  = blockIdx.x * 256 + w * 64;

    short8 Bf[4][2];
    const unsigned short* wb = wf_bf + (size_t)b * 4096;
    #pragma unroll
    for (int ot = 0; ot < 4; ++ot)
        #pragma unroll
        for (int s = 0; s < 2; ++s)
            Bf[ot][s] = *(const short8*)(wb + (size_t)(ot * 16 + l15) * 64
                                         + s * 32 + lg * 8);
    float bias[4];
    #pragma unroll
    for (int ot = 0; ot < 4; ++ot) bias[ot] = b_out[ot * 16 + l15];

    short8 Af[4][2];
    const unsigned short* xr = xT + ((size_t)by * N + nb) * 64;
    #pragma unroll
    for (int mt = 0; mt < 4; ++mt)
        #pragma unroll
        for (int s = 0; s < 2; ++s)
            Af[mt][s] = *(const short8*)(xr + (size_t)(mt * 16 + l15) * 64
                                         + s * 32 + lg * 8);

    float* yb = y + (size_t)b * C_IN * N;
    #pragma unroll
    for (int mt = 0; mt < 4; ++mt) {
        #pragma unroll
        for (int ot = 0; ot < 4; ++ot) {
            f32x4 a = (f32x4){0.f, 0.f, 0.f, 0.f};
            a = __builtin_amdgcn_mfma_f32_16x16x32_bf16(Af[mt][0], Bf[ot][0], a, 0, 0, 0);
            a = __builtin_amdgcn_mfma_f32_16x16x32_bf16(Af[mt][1], Bf[ot][1], a, 0, 0, 0);
            float4 v = make_float4(a[0] + bias[ot], a[1] + bias[ot],
                                   a[2] + bias[ot], a[3] + bias[ot]);
            *(float4*)(yb + (size_t)(ot * 16 + l15) * N + nb + mt * 16 + lg * 4) = v;
        }
    }
}

// ---------------------------------------------------------------------------
extern "C" void kernel_launch(void* const* d_in, const int* in_sizes, int n_in,
                              void* d_out, int out_size, void* d_ws, size_t ws_size,
                              hipStream_t stream)
{
    const float* x     = (const float*)d_in[0];
    const float* w_qkv = (const float*)d_in[1];
    const float* w_out = (const float*)d_in[2];
    const float* b_out = (const float*)d_in[3];
    float* y = (float*)d_out;

    const int B = 2;
    const int N = in_sizes[0] / (B * C_IN);   // 110592
    const int nblk = N / 256;                 // 432

    const size_t xT_batch = (size_t)N * 64 * 2;            // bf16 bytes per batch
    const size_t part_b   = (size_t)B * nblk * 4224 * 4;
    const size_t p2_b     = (size_t)B * 16 * 4224 * 4;
    const size_t wf_b     = (size_t)B * 4096 * 2;
    const bool   full     = ws_size >= (size_t)B * xT_batch + part_b + p2_b + wf_b;

    unsigned short* xT    = (unsigned short*)d_ws;
    char* p               = (char*)d_ws + (full ? B * xT_batch : xT_batch);
    float* part           = (float*)p;
    float* part2          = part + (size_t)B * nblk * 4224;
    unsigned short* wf_bf = (unsigned short*)(part2 + (size_t)B * 16 * 4224);

    if (full) {
        transpose_kernel<<<dim3(N / 64, B), 256, 0, stream>>>(x, xT, N, 0);
        kv_ctx_mfma<<<dim3(nblk, B), 256, 0, stream>>>(xT, w_qkv, part, N, nblk, 0);
        reduce_kernel<<<dim3(17, 16, B), 256, 0, stream>>>(part, part2, nblk);
        finalize_kernel<<<dim3(8, B), 256, 0, stream>>>(part2, w_qkv, w_out, wf_bf);
        out_gemm_mfma<<<dim3(nblk, B), 256, 0, stream>>>(xT, wf_bf, b_out, y, N, 0);
    } else {
        for (int b = 0; b < B; ++b) {
            transpose_kernel<<<dim3(N / 64, 1), 256, 0, stream>>>(x, xT, N, b);
            kv_ctx_mfma<<<dim3(nblk, 1), 256, 0, stream>>>(xT, w_qkv, part, N, nblk, b);
        }
        reduce_kernel<<<dim3(17, 16, B), 256, 0, stream>>>(part, part2, nblk);
        finalize_kernel<<<dim3(8, B), 256, 0, stream>>>(part2, w_qkv, w_out, wf_bf);
        for (int b = 0; b < B; ++b) {
            transpose_kernel<<<dim3(N / 64, 1), 256, 0, stream>>>(x, xT, N, b);
            out_gemm_mfma<<<dim3(nblk, 1), 256, 0, stream>>>(xT, wf_bf, b_out, y, N, b);
        }
    }
}

// Round 15
// 67.807 us; speedup vs baseline: 1.1857x; 1.1857x over previous
//
#include <hip/hip_runtime.h>

// LinearAttention: b=2, c=64, N=48^3=110592, HEADS=4, DIM_HEAD=32.
//
//   y[o,n] = sum_c Wf[b][o,c] x[c,n] + b_out[o]
//   Wf[b]  = w_out · T,  T[h,e,c] = sum_d ctx[h,d,e]·Wq[h*32+d,c]
//   ctx[h,d,e] = (sum_n exp(k[d,n]) v[e,n]) / (sum_n exp(k[d,n]))
// exp without max-subtraction: k ~ N(0,0.16) (verified rounds 2-14).
//
// Round-15: round-13 structure (best: 68.0us) + ONE change: the two in-loop
// __syncthreads() in kv become raw s_barrier with lgkmcnt(0)-only waits.
// hipcc's __syncthreads emits s_waitcnt vmcnt(0) lgkmcnt(0) before s_barrier,
// which drained the issue-early prefetch loads AND the xT stores every
// iteration (~700cy x 4 un-hidden HBM latency per block). Barriers here only
// protect LDS -> lgkmcnt(0) suffices; prefetch regs get compiler-inserted
// vmcnt(N) at first use; xT stores are only read by later kernels.
// (Round-14 lesson: separate transpose+barrier-free kv = WORSE, 80us —
// extra 85MB pass; kv was ~33us even barrier-free -> drain wasn't sole cost,
// but fused+undrained should beat both.)

#define C_IN 64

typedef __attribute__((ext_vector_type(8))) short short8;
typedef __attribute__((ext_vector_type(4))) float f32x4;

static __device__ __forceinline__ unsigned short f2bf(float f) {
    union { float f; unsigned u; } x; x.f = f;
    return (unsigned short)((x.u + 0x7fffu + ((x.u >> 16) & 1u)) >> 16); // RNE
}

// LDS-only barrier: wait LDS ops, then s_barrier — WITHOUT vmcnt(0) drain.
static __device__ __forceinline__ void lds_barrier() {
    __builtin_amdgcn_sched_barrier(0);
    asm volatile("s_waitcnt lgkmcnt(0)" ::: "memory");
    __builtin_amdgcn_s_barrier();
    __builtin_amdgcn_sched_barrier(0);
}

// ---------------------------------------------------------------------------
// Kernel 1 (fused, pipelined): block = 256 n of one batch, wave = head.
//  per 64-n tile: [phase A] bf16 LDS transpose rows -> Xbf + xT global;
//  [phase B] two 32-n halves: {MFMA-1 (K/V) + exp + PV} then {MFMA-2 (ctx)}.
//  PV per-wave private (no barrier). Loads for it+1 issued before A(it),
//  LDS-written at end of B(it). 2 LDS-barriers/iter, 38.4 KB LDS.
//  Output: part[(b*nblk+bx)*4224]: [0..4095]=ctx, [4096..4223]=S.
// ---------------------------------------------------------------------------
__global__ __launch_bounds__(256, 2)
void kv_ctx_fused(const float* __restrict__ x,
                  const float* __restrict__ w_qkv,
                  unsigned short* __restrict__ xT,
                  float* __restrict__ part,
                  int N, int nblk, int bbase)
{
    __shared__ __align__(16) unsigned short Xsb[64][68];   // bf16 [c][n]  8.7 KB
    __shared__ __align__(16) unsigned short Xbf[64][72];   // bf16 [n][c]  9.2 KB
    __shared__ __align__(16) char PVs[4 * 2 * 32 * 80];    // 20.5 KB (pitch 80B)

    const int by  = blockIdx.y;
    const int b   = by + bbase;
    const int bx  = blockIdx.x;
    const int t   = threadIdx.x;
    const int w   = t >> 6;         // wave id = head
    const int l   = t & 63;
    const int l15 = l & 15;
    const int lg  = l >> 4;         // 0..3

    const float* xb = x + (size_t)b * C_IN * N;
    const int n_blk = bx * 256;

    // per-wave-private PV: type p (0=P,1=V), row 0..31, col bf16 0..31
    auto pv_ptr = [&](int p, int row, int colbf) -> unsigned short* {
        return (unsigned short*)(PVs + ((size_t)((w * 2 + p) * 32 + row) * 80
                                        + colbf * 2));
    };

    // ---- weight B-frags: nt 0,1 = K rows, nt 2,3 = V rows; s = K32 slab
    short8 Wfr[4][2];
    #pragma unroll
    for (int nt = 0; nt < 4; ++nt) {
        const int row = (nt < 2) ? (128 + w * 32 + nt * 16 + l15)
                                 : (256 + w * 32 + (nt - 2) * 16 + l15);
        const float* wr = w_qkv + (size_t)row * C_IN;
        #pragma unroll
        for (int s = 0; s < 2; ++s) {
            #pragma unroll
            for (int j = 0; j < 8; ++j)
                Wfr[nt][s][j] = (short)f2bf(wr[s * 32 + lg * 8 + j]);
        }
    }

    f32x4 acc2[2][2];
    #pragma unroll
    for (int dt = 0; dt < 2; ++dt)
        #pragma unroll
        for (int et = 0; et < 2; ++et)
            acc2[dt][et] = (f32x4){0.f, 0.f, 0.f, 0.f};
    float s_loc[2] = {0.f, 0.f};

    float4 ld0, ld1, ld2, ld3;   // staged global tile (16 f32)

    #define ISSUE_LOADS(IT) {                                              \
        const int nb2 = n_blk + (IT) * 64;                                 \
        int slot, c, nq;                                                   \
        slot = 0 * 256 + t; c = slot >> 4; nq = slot & 15;                 \
        ld0 = *(const float4*)(xb + (size_t)c * N + nb2 + nq * 4);         \
        slot = 1 * 256 + t; c = slot >> 4; nq = slot & 15;                 \
        ld1 = *(const float4*)(xb + (size_t)c * N + nb2 + nq * 4);         \
        slot = 2 * 256 + t; c = slot >> 4; nq = slot & 15;                 \
        ld2 = *(const float4*)(xb + (size_t)c * N + nb2 + nq * 4);         \
        slot = 3 * 256 + t; c = slot >> 4; nq = slot & 15;                 \
        ld3 = *(const float4*)(xb + (size_t)c * N + nb2 + nq * 4);         \
    }
    #define STORE_XSB() {                                                  \
        float4 lds_[4] = {ld0, ld1, ld2, ld3};                             \
        _Pragma("unroll")                                                  \
        for (int i = 0; i < 4; ++i) {                                      \
            int slot = i * 256 + t;                                        \
            int c = slot >> 4, n4 = (slot & 15) * 4;                       \
            uint2 p;                                                       \
            p.x = (unsigned)f2bf(lds_[i].x) | ((unsigned)f2bf(lds_[i].y) << 16); \
            p.y = (unsigned)f2bf(lds_[i].z) | ((unsigned)f2bf(lds_[i].w) << 16); \
            *(uint2*)&Xsb[c][n4] = p;                                      \
        }                                                                  \
    }

    // prologue: stage tile 0
    ISSUE_LOADS(0)
    STORE_XSB()
    lds_barrier();

    for (int it = 0; it < 4; ++it) {
        if (it < 3) ISSUE_LOADS(it + 1)   // stays in flight across barriers

        // ---- phase A: Xsb columns -> bf16 rows (Xbf) + xT global
        {
            const int an = l;            // row n (64 per wave), wave = c-stripe
            unsigned rowu[8];
            #pragma unroll
            for (int i = 0; i < 8; ++i) {
                unsigned lo = Xsb[w * 16 + 2 * i][an];
                unsigned hi = Xsb[w * 16 + 2 * i + 1][an];
                rowu[i] = lo | (hi << 16);
            }
            *(uint4*)&Xbf[an][w * 16]     = *(uint4*)&rowu[0];
            *(uint4*)&Xbf[an][w * 16 + 8] = *(uint4*)&rowu[4];
            unsigned short* dst = xT + ((size_t)by * N + n_blk + it * 64 + an) * 64 + w * 16;
            *(uint4*)(dst)     = *(uint4*)&rowu[0];
            *(uint4*)(dst + 8) = *(uint4*)&rowu[4];
        }
        lds_barrier();   // Xbf ready; Xsb fully consumed (LDS only — no vmcnt drain)

        // ---- phase B: A-frags, then two 32-n halves of {MFMA-1, PV, MFMA-2}
        short8 Af[4][2];
        #pragma unroll
        for (int mt = 0; mt < 4; ++mt)
            #pragma unroll
            for (int s = 0; s < 2; ++s)
                Af[mt][s] = *(const short8*)&Xbf[mt * 16 + l15][s * 32 + lg * 8];

        #pragma unroll
        for (int h = 0; h < 2; ++h) {
            // MFMA-1 for this half's two m-tiles; pack P/V rows (n-within-half)
            #pragma unroll
            for (int m2 = 0; m2 < 2; ++m2) {
                const int mt = h * 2 + m2;
                #pragma unroll
                for (int nt = 0; nt < 4; ++nt) {
                    f32x4 a = (f32x4){0.f, 0.f, 0.f, 0.f};
                    a = __builtin_amdgcn_mfma_f32_16x16x32_bf16(Af[mt][0], Wfr[nt][0], a, 0, 0, 0);
                    a = __builtin_amdgcn_mfma_f32_16x16x32_bf16(Af[mt][1], Wfr[nt][1], a, 0, 0, 0);
                    const int nh = m2 * 16 + lg * 4;   // n within half (0..31)
                    if (nt < 2) {
                        float e0 = __expf(a[0]), e1 = __expf(a[1]);
                        float e2 = __expf(a[2]), e3 = __expf(a[3]);
                        s_loc[nt] += (e0 + e1) + (e2 + e3);
                        uint2 p;
                        p.x = (unsigned)f2bf(e0) | ((unsigned)f2bf(e1) << 16);
                        p.y = (unsigned)f2bf(e2) | ((unsigned)f2bf(e3) << 16);
                        *(uint2*)pv_ptr(0, nt * 16 + l15, nh) = p;
                    } else {
                        uint2 p;
                        p.x = (unsigned)f2bf(a[0]) | ((unsigned)f2bf(a[1]) << 16);
                        p.y = (unsigned)f2bf(a[2]) | ((unsigned)f2bf(a[3]) << 16);
                        *(uint2*)pv_ptr(1, (nt - 2) * 16 + l15, nh) = p;
                    }
                }
            }
            // MFMA-2: ctx += P·V^T over this half's 32 n (K=32, intra-wave;
            // compiler inserts fine-grained lgkmcnt for the ds_read->MFMA dep)
            {
                short8 A2[2], B2[2];
                #pragma unroll
                for (int dt = 0; dt < 2; ++dt)
                    A2[dt] = *(const short8*)pv_ptr(0, dt * 16 + l15, lg * 8);
                #pragma unroll
                for (int et = 0; et < 2; ++et)
                    B2[et] = *(const short8*)pv_ptr(1, et * 16 + l15, lg * 8);
                #pragma unroll
                for (int dt = 0; dt < 2; ++dt)
                    #pragma unroll
                    for (int et = 0; et < 2; ++et)
                        acc2[dt][et] = __builtin_amdgcn_mfma_f32_16x16x32_bf16(
                            A2[dt], B2[et], acc2[dt][et], 0, 0, 0);
            }
        }

        if (it < 3) STORE_XSB()   // vmcnt(N) auto-inserted before ld use
        lds_barrier();            // Xsb(it+1) ready; Xbf consumed (LDS only)
    }
    #undef ISSUE_LOADS
    #undef STORE_XSB

    // ---- plain per-block partial stores (no atomics, no zeroing)
    float* pb = part + ((size_t)b * nblk + bx) * 4224;
    #pragma unroll
    for (int dt = 0; dt < 2; ++dt)
        #pragma unroll
        for (int et = 0; et < 2; ++et)
            #pragma unroll
            for (int r = 0; r < 4; ++r)
                pb[(w * 32 + dt * 16 + lg * 4 + r) * 32 + et * 16 + l15] =
                    acc2[dt][et][r];

    #pragma unroll
    for (int nt = 0; nt < 2; ++nt) {
        float s = s_loc[nt];
        s += __shfl_xor(s, 16);
        s += __shfl_xor(s, 32);
        if (lg == 0)
            pb[4096 + w * 32 + nt * 16 + l15] = s;
    }
}

// ---------------------------------------------------------------------------
// Kernel 2: parallel partial reduce. grid (17, 16, B): block sums ~nblk/16
// chunks (coalesced over g) -> part2[b][16][4224].
// ---------------------------------------------------------------------------
__global__ __launch_bounds__(256)
void reduce_kernel(const float* __restrict__ part,
                   float* __restrict__ part2,
                   int nblk)
{
    const int b  = blockIdx.z;
    const int cy = blockIdx.y;          // 0..15
    const int g  = blockIdx.x * 256 + threadIdx.x;
    if (g >= 4224) return;

    const int cnt = (nblk + 15) / 16;
    const int c0  = cy * cnt;
    const int c1  = (c0 + cnt < nblk) ? (c0 + cnt) : nblk;

    const float* pb = part + (size_t)b * nblk * 4224 + g;
    float a0 = 0.f, a1 = 0.f, a2 = 0.f, a3 = 0.f;
    int c = c0;
    for (; c + 4 <= c1; c += 4) {
        a0 += pb[(size_t)(c + 0) * 4224];
        a1 += pb[(size_t)(c + 1) * 4224];
        a2 += pb[(size_t)(c + 2) * 4224];
        a3 += pb[(size_t)(c + 3) * 4224];
    }
    for (; c < c1; ++c) a0 += pb[(size_t)c * 4224];
    part2[((size_t)b * 16 + cy) * 4224 + g] = (a0 + a1) + (a2 + a3);
}

// ---------------------------------------------------------------------------
// Kernel 3: merge 16 replicas, normalize ctx, T = ctx·Wq, Wf = w_out·T -> bf16.
// grid (8, B): block s writes o-rows [8s, 8s+8) of Wf.
// ---------------------------------------------------------------------------
__global__ __launch_bounds__(256)
void finalize_kernel(const float* __restrict__ part2,
                     const float* __restrict__ w_qkv,
                     const float* __restrict__ w_out,
                     unsigned short* __restrict__ wf_bf)
{
    const int b = blockIdx.y;
    const int s = blockIdx.x;
    const int t = threadIdx.x;

    __shared__ float Wq[128][64];
    __shared__ float Ctx[128][36];
    __shared__ float Tt[128][68];
    __shared__ float WoS[8][128];
    __shared__ float Sinv[128];

    #pragma unroll
    for (int i = 0; i < 8; ++i) {
        int idx = i * 1024 + t * 4;
        *(float4*)&Wq[idx >> 6][idx & 63] = *(const float4*)(w_qkv + idx);
    }
    {
        int idx = t * 4;
        int o = idx >> 7, he = idx & 127;
        *(float4*)&WoS[o][he] = *(const float4*)(w_out + (size_t)(s * 8 + o) * 128 + he);
    }
    if (t < 128) {
        float ssum = 0.f;
        #pragma unroll
        for (int rep = 0; rep < 16; ++rep)
            ssum += part2[((size_t)b * 16 + rep) * 4224 + 4096 + t];
        Sinv[t] = 1.0f / ssum;
    }
    float cacc[16];
    #pragma unroll
    for (int i = 0; i < 16; ++i) cacc[i] = 0.f;
    {
        const float* cb = part2 + (size_t)b * 16 * 4224;
        for (int rep = 0; rep < 16; ++rep) {
            #pragma unroll
            for (int i = 0; i < 16; ++i)
                cacc[i] += cb[(size_t)rep * 4224 + i * 256 + t];
        }
    }
    __syncthreads();   // Sinv ready

    #pragma unroll
    for (int i = 0; i < 16; ++i) {
        int idx = i * 256 + t;          // hd*32 + e
        Ctx[idx >> 5][idx & 31] = cacc[i] * Sinv[idx >> 5];
    }
    __syncthreads();

    // ---- T: thread owns 4he x 8c tile; per d: 3 b128 reads -> 32 FMA
    {
        const int he0 = (t >> 3) * 4;
        const int c0  = (t & 7) * 8;
        const int hh  = he0 >> 5;
        const int e0  = he0 & 31;
        float acc[4][8];
        #pragma unroll
        for (int j = 0; j < 4; ++j)
            #pragma unroll
            for (int k = 0; k < 8; ++k) acc[j][k] = 0.f;

        for (int d = 0; d < 32; ++d) {
            float4 cv = *(const float4*)&Ctx[hh * 32 + d][e0];
            float4 w0 = *(const float4*)&Wq[hh * 32 + d][c0];
            float4 w1 = *(const float4*)&Wq[hh * 32 + d][c0 + 4];
            float wv[8] = {w0.x, w0.y, w0.z, w0.w, w1.x, w1.y, w1.z, w1.w};
            float cvv[4] = {cv.x, cv.y, cv.z, cv.w};
            #pragma unroll
            for (int j = 0; j < 4; ++j)
                #pragma unroll
                for (int k = 0; k < 8; ++k)
                    acc[j][k] = fmaf(cvv[j], wv[k], acc[j][k]);
        }
        #pragma unroll
        for (int j = 0; j < 4; ++j) {
            *(float4*)&Tt[he0 + j][c0]     = make_float4(acc[j][0], acc[j][1], acc[j][2], acc[j][3]);
            *(float4*)&Tt[he0 + j][c0 + 4] = make_float4(acc[j][4], acc[j][5], acc[j][6], acc[j][7]);
        }
    }
    __syncthreads();

    // ---- Wf slice: thread -> (o = 8s + t>>5, c = 2*(t&31)); 128-he dot
    {
        const int o = t >> 5;
        const int c = (t & 31) * 2;
        float a0 = 0.f, a1 = 0.f, b0 = 0.f, b1 = 0.f;
        #pragma unroll
        for (int he = 0; he < 128; he += 2) {
            float w0 = WoS[o][he], w1 = WoS[o][he + 1];
            float2 t0 = *(const float2*)&Tt[he][c];
            float2 t1 = *(const float2*)&Tt[he + 1][c];
            a0 = fmaf(w0, t0.x, a0); a1 = fmaf(w0, t0.y, a1);
            b0 = fmaf(w1, t1.x, b0); b1 = fmaf(w1, t1.y, b1);
        }
        unsigned short* dst = wf_bf + (size_t)b * 4096 + (size_t)(s * 8 + o) * 64 + c;
        dst[0] = f2bf(a0 + b0);
        dst[1] = f2bf(a1 + b1);
    }
}

// ---------------------------------------------------------------------------
// Kernel 4: y = Wf·x + b via MFMA. Wave covers 64 n x all 64 o.
// ---------------------------------------------------------------------------
__global__ __launch_bounds__(256)
void out_gemm_mfma(const unsigned short* __restrict__ xT,
                   const unsigned short* __restrict__ wf_bf,  // [B][64o][64c]
                   const float* __restrict__ b_out,
                   float* __restrict__ y,
                   int N, int bbase)
{
    const int by  = blockIdx.y;
    const int b   = by + bbase;
    const int t   = threadIdx.x;
    const int w   = t >> 6;
    const int l   = t & 63;
    const int l15 = l & 15;
    const int lg  = l >> 4;
    const int nb  = blockIdx.x * 256 + w * 64;

    short8 Bf[4][2];
    const unsigned short* wb = wf_bf + (size_t)b * 4096;
    #pragma unroll
    for (int ot = 0; ot < 4; ++ot)
        #pragma unroll
        for (int s = 0; s < 2; ++s)
            Bf[ot][s] = *(const short8*)(wb + (size_t)(ot * 16 + l15) * 64
                                         + s * 32 + lg * 8);
    float bias[4];
    #pragma unroll
    for (int ot = 0; ot < 4; ++ot) bias[ot] = b_out[ot * 16 + l15];

    short8 Af[4][2];
    const unsigned short* xr = xT + ((size_t)by * N + nb) * 64;
    #pragma unroll
    for (int mt = 0; mt < 4; ++mt)
        #pragma unroll
        for (int s = 0; s < 2; ++s)
            Af[mt][s] = *(const short8*)(xr + (size_t)(mt * 16 + l15) * 64
                                         + s * 32 + lg * 8);

    float* yb = y + (size_t)b * C_IN * N;
    #pragma unroll
    for (int mt = 0; mt < 4; ++mt) {
        #pragma unroll
        for (int ot = 0; ot < 4; ++ot) {
            f32x4 a = (f32x4){0.f, 0.f, 0.f, 0.f};
            a = __builtin_amdgcn_mfma_f32_16x16x32_bf16(Af[mt][0], Bf[ot][0], a, 0, 0, 0);
            a = __builtin_amdgcn_mfma_f32_16x16x32_bf16(Af[mt][1], Bf[ot][1], a, 0, 0, 0);
            float4 v = make_float4(a[0] + bias[ot], a[1] + bias[ot],
                                   a[2] + bias[ot], a[3] + bias[ot]);
            *(float4*)(yb + (size_t)(ot * 16 + l15) * N + nb + mt * 16 + lg * 4) = v;
        }
    }
}

// ---------------------------------------------------------------------------
// Fallback-only: standalone x -> xT transpose (used when ws can't hold 2 xT).
// ---------------------------------------------------------------------------
__global__ __launch_bounds__(256)
void transpose_kernel(const float* __restrict__ x,
                      unsigned short* __restrict__ xT,
                      int N, int bbase)
{
    __shared__ float Xs[64][65];
    const int b  = blockIdx.y + bbase;
    const int t  = threadIdx.x;
    const int n0 = blockIdx.x * 64;

    const float* xb = x + (size_t)b * C_IN * N;
    #pragma unroll
    for (int i = 0; i < 4; ++i) {
        int slot = i * 256 + t;
        int c = slot >> 4, nq = slot & 15;
        float4 v = *(const float4*)(xb + (size_t)c * N + n0 + nq * 4);
        Xs[c][nq * 4 + 0] = v.x; Xs[c][nq * 4 + 1] = v.y;
        Xs[c][nq * 4 + 2] = v.z; Xs[c][nq * 4 + 3] = v.w;
    }
    __syncthreads();

    const int n = t >> 2, q = t & 3;
    unsigned out[8];
    #pragma unroll
    for (int i = 0; i < 8; ++i) {
        float lo = Xs[q * 16 + 2 * i][n], hi = Xs[q * 16 + 2 * i + 1][n];
        out[i] = (unsigned)f2bf(lo) | ((unsigned)f2bf(hi) << 16);
    }
    unsigned short* dst = xT + ((size_t)blockIdx.y * N + n0 + n) * 64 + q * 16;
    *(uint4*)(dst)     = *(uint4*)&out[0];
    *(uint4*)(dst + 8) = *(uint4*)&out[4];
}

// ---------------------------------------------------------------------------
extern "C" void kernel_launch(void* const* d_in, const int* in_sizes, int n_in,
                              void* d_out, int out_size, void* d_ws, size_t ws_size,
                              hipStream_t stream)
{
    const float* x     = (const float*)d_in[0];
    const float* w_qkv = (const float*)d_in[1];
    const float* w_out = (const float*)d_in[2];
    const float* b_out = (const float*)d_in[3];
    float* y = (float*)d_out;

    const int B = 2;
    const int N = in_sizes[0] / (B * C_IN);   // 110592
    const int nblk = N / 256;                 // 432

    const size_t xT_batch = (size_t)N * 64 * 2;            // bf16 bytes per batch
    const size_t part_b   = (size_t)B * nblk * 4224 * 4;
    const size_t p2_b     = (size_t)B * 16 * 4224 * 4;
    const size_t wf_b     = (size_t)B * 4096 * 2;
    const bool   full     = ws_size >= (size_t)B * xT_batch + part_b + p2_b + wf_b;

    unsigned short* xT    = (unsigned short*)d_ws;
    char* p               = (char*)d_ws + (full ? B * xT_batch : xT_batch);
    float* part           = (float*)p;
    float* part2          = part + (size_t)B * nblk * 4224;
    unsigned short* wf_bf = (unsigned short*)(part2 + (size_t)B * 16 * 4224);

    if (full) {
        kv_ctx_fused<<<dim3(nblk, B), 256, 0, stream>>>(x, w_qkv, xT, part, N, nblk, 0);
        reduce_kernel<<<dim3(17, 16, B), 256, 0, stream>>>(part, part2, nblk);
        finalize_kernel<<<dim3(8, B), 256, 0, stream>>>(part2, w_qkv, w_out, wf_bf);
        out_gemm_mfma<<<dim3(nblk, B), 256, 0, stream>>>(xT, wf_bf, b_out, y, N, 0);
    } else {
        for (int b = 0; b < B; ++b)
            kv_ctx_fused<<<dim3(nblk, 1), 256, 0, stream>>>(x, w_qkv, xT, part, N, nblk, b);
        reduce_kernel<<<dim3(17, 16, B), 256, 0, stream>>>(part, part2, nblk);
        finalize_kernel<<<dim3(8, B), 256, 0, stream>>>(part2, w_qkv, w_out, wf_bf);
        for (int b = 0; b < B; ++b) {
            transpose_kernel<<<dim3(N / 64, 1), 256, 0, stream>>>(x, xT, N, b);
            out_gemm_mfma<<<dim3(nblk, 1), 256, 0, stream>>>(xT, wf_bf, b_out, y, N, b);
        }
    }
}

// Round 17
// 66.273 us; speedup vs baseline: 1.2131x; 1.0231x over previous
//
#include <hip/hip_runtime.h>
#include <hip/hip_bf16.h>

// LinearAttention: b=2, c=64, N=48^3=110592, HEADS=4, DIM_HEAD=32.
//
//   y[o,n] = sum_c Wf[b][o,c] x[c,n] + b_out[o]
//   Wf[b]  = w_out · T,  T[h,e,c] = sum_d ctx[h,d,e]·Wq[h*32+d,c]
//   ctx[h,d,e] = (sum_n exp(k[d,n]) v[e,n]) / (sum_n exp(k[d,n]))
// exp without max-subtraction: k ~ N(0,0.16) (verified rounds 2-15).
//
// Round-17: round-16's inline-asm v_cvt_pk_bf16_f32 produced NaN (wrong
// encoding/semantics on this compiler — m240's "don't hand-write cvt_pk"
// lesson). Same packing now via __float22bfloat162_rn (HIP intrinsic, RNE,
// x->low16 y->high16 — bit-identical to the proven f2bf pair); hipcc picks
// the packed hw convert itself. Structure = round 15 (67.8us).

#define C_IN 64

typedef __attribute__((ext_vector_type(8))) short short8;
typedef __attribute__((ext_vector_type(4))) float f32x4;

static __device__ __forceinline__ unsigned short f2bf(float f) {
    union { float f; unsigned u; } x; x.f = f;
    return (unsigned short)((x.u + 0x7fffu + ((x.u >> 16) & 1u)) >> 16); // RNE
}

// packed f32x2 -> bf16x2 via HIP intrinsic (compiler emits packed cvt)
static __device__ __forceinline__ unsigned cvt_pk_bf16(float lo, float hi) {
    __hip_bfloat162 h = __float22bfloat162_rn(float2{lo, hi});
    union { __hip_bfloat162 h; unsigned u; } cv;
    cv.h = h;
    return cv.u;
}

// LDS-only barrier: wait LDS ops, then s_barrier — WITHOUT vmcnt(0) drain.
static __device__ __forceinline__ void lds_barrier() {
    __builtin_amdgcn_sched_barrier(0);
    asm volatile("s_waitcnt lgkmcnt(0)" ::: "memory");
    __builtin_amdgcn_s_barrier();
    __builtin_amdgcn_sched_barrier(0);
}

// ---------------------------------------------------------------------------
// Kernel 1 (fused, pipelined): block = 256 n of one batch, wave = head.
//  per 64-n tile: [phase A] bf16 LDS transpose rows -> Xbf + xT global;
//  [phase B] two 32-n halves: {MFMA-1 (K/V) + exp + PV} then {MFMA-2 (ctx)}.
//  PV per-wave private (no barrier). Loads for it+1 issued before A(it),
//  LDS-written at end of B(it). 2 LDS-barriers/iter, 38.4 KB LDS.
//  Output: part[(b*nblk+bx)*4224]: [0..4095]=ctx, [4096..4223]=S.
// ---------------------------------------------------------------------------
__global__ __launch_bounds__(256, 2)
void kv_ctx_fused(const float* __restrict__ x,
                  const float* __restrict__ w_qkv,
                  unsigned short* __restrict__ xT,
                  float* __restrict__ part,
                  int N, int nblk, int bbase)
{
    __shared__ __align__(16) unsigned short Xsb[64][68];   // bf16 [c][n]  8.7 KB
    __shared__ __align__(16) unsigned short Xbf[64][72];   // bf16 [n][c]  9.2 KB
    __shared__ __align__(16) char PVs[4 * 2 * 32 * 80];    // 20.5 KB (pitch 80B)

    const int by  = blockIdx.y;
    const int b   = by + bbase;
    const int bx  = blockIdx.x;
    const int t   = threadIdx.x;
    const int w   = t >> 6;         // wave id = head
    const int l   = t & 63;
    const int l15 = l & 15;
    const int lg  = l >> 4;         // 0..3

    const float* xb = x + (size_t)b * C_IN * N;
    const int n_blk = bx * 256;

    // per-wave-private PV: type p (0=P,1=V), row 0..31, col bf16 0..31
    auto pv_ptr = [&](int p, int row, int colbf) -> unsigned short* {
        return (unsigned short*)(PVs + ((size_t)((w * 2 + p) * 32 + row) * 80
                                        + colbf * 2));
    };

    // ---- weight B-frags: nt 0,1 = K rows, nt 2,3 = V rows; s = K32 slab
    short8 Wfr[4][2];
    #pragma unroll
    for (int nt = 0; nt < 4; ++nt) {
        const int row = (nt < 2) ? (128 + w * 32 + nt * 16 + l15)
                                 : (256 + w * 32 + (nt - 2) * 16 + l15);
        const float* wr = w_qkv + (size_t)row * C_IN;
        #pragma unroll
        for (int s = 0; s < 2; ++s) {
            #pragma unroll
            for (int j = 0; j < 8; ++j)
                Wfr[nt][s][j] = (short)f2bf(wr[s * 32 + lg * 8 + j]);
        }
    }

    f32x4 acc2[2][2];
    #pragma unroll
    for (int dt = 0; dt < 2; ++dt)
        #pragma unroll
        for (int et = 0; et < 2; ++et)
            acc2[dt][et] = (f32x4){0.f, 0.f, 0.f, 0.f};
    float s_loc[2] = {0.f, 0.f};

    float4 ld0, ld1, ld2, ld3;   // staged global tile (16 f32)

    #define ISSUE_LOADS(IT) {                                              \
        const int nb2 = n_blk + (IT) * 64;                                 \
        int slot, c, nq;                                                   \
        slot = 0 * 256 + t; c = slot >> 4; nq = slot & 15;                 \
        ld0 = *(const float4*)(xb + (size_t)c * N + nb2 + nq * 4);         \
        slot = 1 * 256 + t; c = slot >> 4; nq = slot & 15;                 \
        ld1 = *(const float4*)(xb + (size_t)c * N + nb2 + nq * 4);         \
        slot = 2 * 256 + t; c = slot >> 4; nq = slot & 15;                 \
        ld2 = *(const float4*)(xb + (size_t)c * N + nb2 + nq * 4);         \
        slot = 3 * 256 + t; c = slot >> 4; nq = slot & 15;                 \
        ld3 = *(const float4*)(xb + (size_t)c * N + nb2 + nq * 4);         \
    }
    #define STORE_XSB() {                                                  \
        float4 lds_[4] = {ld0, ld1, ld2, ld3};                             \
        _Pragma("unroll")                                                  \
        for (int i = 0; i < 4; ++i) {                                      \
            int slot = i * 256 + t;                                        \
            int c = slot >> 4, n4 = (slot & 15) * 4;                       \
            uint2 p;                                                       \
            p.x = cvt_pk_bf16(lds_[i].x, lds_[i].y);                       \
            p.y = cvt_pk_bf16(lds_[i].z, lds_[i].w);                       \
            *(uint2*)&Xsb[c][n4] = p;                                      \
        }                                                                  \
    }

    // prologue: stage tile 0
    ISSUE_LOADS(0)
    STORE_XSB()
    lds_barrier();

    for (int it = 0; it < 4; ++it) {
        if (it < 3) ISSUE_LOADS(it + 1)   // stays in flight across barriers

        // ---- phase A: Xsb columns -> bf16 rows (Xbf) + xT global
        {
            const int an = l;            // row n (64 per wave), wave = c-stripe
            unsigned rowu[8];
            #pragma unroll
            for (int i = 0; i < 8; ++i) {
                unsigned lo = Xsb[w * 16 + 2 * i][an];
                unsigned hi = Xsb[w * 16 + 2 * i + 1][an];
                rowu[i] = lo | (hi << 16);
            }
            *(uint4*)&Xbf[an][w * 16]     = *(uint4*)&rowu[0];
            *(uint4*)&Xbf[an][w * 16 + 8] = *(uint4*)&rowu[4];
            unsigned short* dst = xT + ((size_t)by * N + n_blk + it * 64 + an) * 64 + w * 16;
            *(uint4*)(dst)     = *(uint4*)&rowu[0];
            *(uint4*)(dst + 8) = *(uint4*)&rowu[4];
        }
        lds_barrier();   // Xbf ready; Xsb fully consumed (LDS only)

        // ---- phase B: A-frags, then two 32-n halves of {MFMA-1, PV, MFMA-2}
        short8 Af[4][2];
        #pragma unroll
        for (int mt = 0; mt < 4; ++mt)
            #pragma unroll
            for (int s = 0; s < 2; ++s)
                Af[mt][s] = *(const short8*)&Xbf[mt * 16 + l15][s * 32 + lg * 8];

        #pragma unroll
        for (int h = 0; h < 2; ++h) {
            // MFMA-1 for this half's two m-tiles; pack P/V rows (n-within-half)
            #pragma unroll
            for (int m2 = 0; m2 < 2; ++m2) {
                const int mt = h * 2 + m2;
                #pragma unroll
                for (int nt = 0; nt < 4; ++nt) {
                    f32x4 a = (f32x4){0.f, 0.f, 0.f, 0.f};
                    a = __builtin_amdgcn_mfma_f32_16x16x32_bf16(Af[mt][0], Wfr[nt][0], a, 0, 0, 0);
                    a = __builtin_amdgcn_mfma_f32_16x16x32_bf16(Af[mt][1], Wfr[nt][1], a, 0, 0, 0);
                    const int nh = m2 * 16 + lg * 4;   // n within half (0..31)
                    if (nt < 2) {
                        float e0 = __expf(a[0]), e1 = __expf(a[1]);
                        float e2 = __expf(a[2]), e3 = __expf(a[3]);
                        s_loc[nt] += (e0 + e1) + (e2 + e3);
                        uint2 p;
                        p.x = cvt_pk_bf16(e0, e1);
                        p.y = cvt_pk_bf16(e2, e3);
                        *(uint2*)pv_ptr(0, nt * 16 + l15, nh) = p;
                    } else {
                        uint2 p;
                        p.x = cvt_pk_bf16(a[0], a[1]);
                        p.y = cvt_pk_bf16(a[2], a[3]);
                        *(uint2*)pv_ptr(1, (nt - 2) * 16 + l15, nh) = p;
                    }
                }
            }
            // MFMA-2: ctx += P·V^T over this half's 32 n (K=32, intra-wave)
            {
                short8 A2[2], B2[2];
                #pragma unroll
                for (int dt = 0; dt < 2; ++dt)
                    A2[dt] = *(const short8*)pv_ptr(0, dt * 16 + l15, lg * 8);
                #pragma unroll
                for (int et = 0; et < 2; ++et)
                    B2[et] = *(const short8*)pv_ptr(1, et * 16 + l15, lg * 8);
                #pragma unroll
                for (int dt = 0; dt < 2; ++dt)
                    #pragma unroll
                    for (int et = 0; et < 2; ++et)
                        acc2[dt][et] = __builtin_amdgcn_mfma_f32_16x16x32_bf16(
                            A2[dt], B2[et], acc2[dt][et], 0, 0, 0);
            }
        }

        if (it < 3) STORE_XSB()   // vmcnt(N) auto-inserted before ld use
        lds_barrier();            // Xsb(it+1) ready; Xbf consumed (LDS only)
    }
    #undef ISSUE_LOADS
    #undef STORE_XSB

    // ---- plain per-block partial stores (no atomics, no zeroing)
    float* pb = part + ((size_t)b * nblk + bx) * 4224;
    #pragma unroll
    for (int dt = 0; dt < 2; ++dt)
        #pragma unroll
        for (int et = 0; et < 2; ++et)
            #pragma unroll
            for (int r = 0; r < 4; ++r)
                pb[(w * 32 + dt * 16 + lg * 4 + r) * 32 + et * 16 + l15] =
                    acc2[dt][et][r];

    #pragma unroll
    for (int nt = 0; nt < 2; ++nt) {
        float s = s_loc[nt];
        s += __shfl_xor(s, 16);
        s += __shfl_xor(s, 32);
        if (lg == 0)
            pb[4096 + w * 32 + nt * 16 + l15] = s;
    }
}

// ---------------------------------------------------------------------------
// Kernel 2: parallel partial reduce. grid (17, 16, B): block sums ~nblk/16
// chunks (coalesced over g) -> part2[b][16][4224].
// ---------------------------------------------------------------------------
__global__ __launch_bounds__(256)
void reduce_kernel(const float* __restrict__ part,
                   float* __restrict__ part2,
                   int nblk)
{
    const int b  = blockIdx.z;
    const int cy = blockIdx.y;          // 0..15
    const int g  = blockIdx.x * 256 + threadIdx.x;
    if (g >= 4224) return;

    const int cnt = (nblk + 15) / 16;
    const int c0  = cy * cnt;
    const int c1  = (c0 + cnt < nblk) ? (c0 + cnt) : nblk;

    const float* pb = part + (size_t)b * nblk * 4224 + g;
    float a0 = 0.f, a1 = 0.f, a2 = 0.f, a3 = 0.f;
    int c = c0;
    for (; c + 4 <= c1; c += 4) {
        a0 += pb[(size_t)(c + 0) * 4224];
        a1 += pb[(size_t)(c + 1) * 4224];
        a2 += pb[(size_t)(c + 2) * 4224];
        a3 += pb[(size_t)(c + 3) * 4224];
    }
    for (; c < c1; ++c) a0 += pb[(size_t)c * 4224];
    part2[((size_t)b * 16 + cy) * 4224 + g] = (a0 + a1) + (a2 + a3);
}

// ---------------------------------------------------------------------------
// Kernel 3: merge 16 replicas, normalize ctx, T = ctx·Wq, Wf = w_out·T -> bf16.
// grid (8, B): block s writes o-rows [8s, 8s+8) of Wf.
// ---------------------------------------------------------------------------
__global__ __launch_bounds__(256)
void finalize_kernel(const float* __restrict__ part2,
                     const float* __restrict__ w_qkv,
                     const float* __restrict__ w_out,
                     unsigned short* __restrict__ wf_bf)
{
    const int b = blockIdx.y;
    const int s = blockIdx.x;
    const int t = threadIdx.x;

    __shared__ float Wq[128][64];
    __shared__ float Ctx[128][36];
    __shared__ float Tt[128][68];
    __shared__ float WoS[8][128];
    __shared__ float Sinv[128];

    #pragma unroll
    for (int i = 0; i < 8; ++i) {
        int idx = i * 1024 + t * 4;
        *(float4*)&Wq[idx >> 6][idx & 63] = *(const float4*)(w_qkv + idx);
    }
    {
        int idx = t * 4;
        int o = idx >> 7, he = idx & 127;
        *(float4*)&WoS[o][he] = *(const float4*)(w_out + (size_t)(s * 8 + o) * 128 + he);
    }
    if (t < 128) {
        float ssum = 0.f;
        #pragma unroll
        for (int rep = 0; rep < 16; ++rep)
            ssum += part2[((size_t)b * 16 + rep) * 4224 + 4096 + t];
        Sinv[t] = 1.0f / ssum;
    }
    float cacc[16];
    #pragma unroll
    for (int i = 0; i < 16; ++i) cacc[i] = 0.f;
    {
        const float* cb = part2 + (size_t)b * 16 * 4224;
        for (int rep = 0; rep < 16; ++rep) {
            #pragma unroll
            for (int i = 0; i < 16; ++i)
                cacc[i] += cb[(size_t)rep * 4224 + i * 256 + t];
        }
    }
    __syncthreads();   // Sinv ready

    #pragma unroll
    for (int i = 0; i < 16; ++i) {
        int idx = i * 256 + t;          // hd*32 + e
        Ctx[idx >> 5][idx & 31] = cacc[i] * Sinv[idx >> 5];
    }
    __syncthreads();

    // ---- T: thread owns 4he x 8c tile; per d: 3 b128 reads -> 32 FMA
    {
        const int he0 = (t >> 3) * 4;
        const int c0  = (t & 7) * 8;
        const int hh  = he0 >> 5;
        const int e0  = he0 & 31;
        float acc[4][8];
        #pragma unroll
        for (int j = 0; j < 4; ++j)
            #pragma unroll
            for (int k = 0; k < 8; ++k) acc[j][k] = 0.f;

        for (int d = 0; d < 32; ++d) {
            float4 cv = *(const float4*)&Ctx[hh * 32 + d][e0];
            float4 w0 = *(const float4*)&Wq[hh * 32 + d][c0];
            float4 w1 = *(const float4*)&Wq[hh * 32 + d][c0 + 4];
            float wv[8] = {w0.x, w0.y, w0.z, w0.w, w1.x, w1.y, w1.z, w1.w};
            float cvv[4] = {cv.x, cv.y, cv.z, cv.w};
            #pragma unroll
            for (int j = 0; j < 4; ++j)
                #pragma unroll
                for (int k = 0; k < 8; ++k)
                    acc[j][k] = fmaf(cvv[j], wv[k], acc[j][k]);
        }
        #pragma unroll
        for (int j = 0; j < 4; ++j) {
            *(float4*)&Tt[he0 + j][c0]     = make_float4(acc[j][0], acc[j][1], acc[j][2], acc[j][3]);
            *(float4*)&Tt[he0 + j][c0 + 4] = make_float4(acc[j][4], acc[j][5], acc[j][6], acc[j][7]);
        }
    }
    __syncthreads();

    // ---- Wf slice: thread -> (o = 8s + t>>5, c = 2*(t&31)); 128-he dot
    {
        const int o = t >> 5;
        const int c = (t & 31) * 2;
        float a0 = 0.f, a1 = 0.f, b0 = 0.f, b1 = 0.f;
        #pragma unroll
        for (int he = 0; he < 128; he += 2) {
            float w0 = WoS[o][he], w1 = WoS[o][he + 1];
            float2 t0 = *(const float2*)&Tt[he][c];
            float2 t1 = *(const float2*)&Tt[he + 1][c];
            a0 = fmaf(w0, t0.x, a0); a1 = fmaf(w0, t0.y, a1);
            b0 = fmaf(w1, t1.x, b0); b1 = fmaf(w1, t1.y, b1);
        }
        unsigned short* dst = wf_bf + (size_t)b * 4096 + (size_t)(s * 8 + o) * 64 + c;
        dst[0] = f2bf(a0 + b0);
        dst[1] = f2bf(a1 + b1);
    }
}

// ---------------------------------------------------------------------------
// Kernel 4: y = Wf·x + b via MFMA. Wave covers 64 n x all 64 o.
// ---------------------------------------------------------------------------
__global__ __launch_bounds__(256)
void out_gemm_mfma(const unsigned short* __restrict__ xT,
                   const unsigned short* __restrict__ wf_bf,  // [B][64o][64c]
                   const float* __restrict__ b_out,
                   float* __restrict__ y,
                   int N, int bbase)
{
    const int by  = blockIdx.y;
    const int b   = by + bbase;
    const int t   = threadIdx.x;
    const int w   = t >> 6;
    const int l   = t & 63;
    const int l15 = l & 15;
    const int lg  = l >> 4;
    const int nb  = blockIdx.x * 256 + w * 64;

    short8 Bf[4][2];
    const unsigned short* wb = wf_bf + (size_t)b * 4096;
    #pragma unroll
    for (int ot = 0; ot < 4; ++ot)
        #pragma unroll
        for (int s = 0; s < 2; ++s)
            Bf[ot][s] = *(const short8*)(wb + (size_t)(ot * 16 + l15) * 64
                                         + s * 32 + lg * 8);
    float bias[4];
    #pragma unroll
    for (int ot = 0; ot < 4; ++ot) bias[ot] = b_out[ot * 16 + l15];

    short8 Af[4][2];
    const unsigned short* xr = xT + ((size_t)by * N + nb) * 64;
    #pragma unroll
    for (int mt = 0; mt < 4; ++mt)
        #pragma unroll
        for (int s = 0; s < 2; ++s)
            Af[mt][s] = *(const short8*)(xr + (size_t)(mt * 16 + l15) * 64
                                         + s * 32 + lg * 8);

    float* yb = y + (size_t)b * C_IN * N;
    #pragma unroll
    for (int mt = 0; mt < 4; ++mt) {
        #pragma unroll
        for (int ot = 0; ot < 4; ++ot) {
            f32x4 a = (f32x4){0.f, 0.f, 0.f, 0.f};
            a = __builtin_amdgcn_mfma_f32_16x16x32_bf16(Af[mt][0], Bf[ot][0], a, 0, 0, 0);
            a = __builtin_amdgcn_mfma_f32_16x16x32_bf16(Af[mt][1], Bf[ot][1], a, 0, 0, 0);
            float4 v = make_float4(a[0] + bias[ot], a[1] + bias[ot],
                                   a[2] + bias[ot], a[3] + bias[ot]);
            *(float4*)(yb + (size_t)(ot * 16 + l15) * N + nb + mt * 16 + lg * 4) = v;
        }
    }
}

// ---------------------------------------------------------------------------
// Fallback-only: standalone x -> xT transpose (used when ws can't hold 2 xT).
// ---------------------------------------------------------------------------
__global__ __launch_bounds__(256)
void transpose_kernel(const float* __restrict__ x,
                      unsigned short* __restrict__ xT,
                      int N, int bbase)
{
    __shared__ float Xs[64][65];
    const int b  = blockIdx.y + bbase;
    const int t  = threadIdx.x;
    const int n0 = blockIdx.x * 64;

    const float* xb = x + (size_t)b * C_IN * N;
    #pragma unroll
    for (int i = 0; i < 4; ++i) {
        int slot = i * 256 + t;
        int c = slot >> 4, nq = slot & 15;
        float4 v = *(const float4*)(xb + (size_t)c * N + n0 + nq * 4);
        Xs[c][nq * 4 + 0] = v.x; Xs[c][nq * 4 + 1] = v.y;
        Xs[c][nq * 4 + 2] = v.z; Xs[c][nq * 4 + 3] = v.w;
    }
    __syncthreads();

    const int n = t >> 2, q = t & 3;
    unsigned out[8];
    #pragma unroll
    for (int i = 0; i < 8; ++i)
        out[i] = cvt_pk_bf16(Xs[q * 16 + 2 * i][n], Xs[q * 16 + 2 * i + 1][n]);
    unsigned short* dst = xT + ((size_t)blockIdx.y * N + n0 + n) * 64 + q * 16;
    *(uint4*)(dst)     = *(uint4*)&out[0];
    *(uint4*)(dst + 8) = *(uint4*)&out[4];
}

// ---------------------------------------------------------------------------
extern "C" void kernel_launch(void* const* d_in, const int* in_sizes, int n_in,
                              void* d_out, int out_size, void* d_ws, size_t ws_size,
                              hipStream_t stream)
{
    const float* x     = (const float*)d_in[0];
    const float* w_qkv = (const float*)d_in[1];
    const float* w_out = (const float*)d_in[2];
    const float* b_out = (const float*)d_in[3];
    float* y = (float*)d_out;

    const int B = 2;
    const int N = in_sizes[0] / (B * C_IN);   // 110592
    const int nblk = N / 256;                 // 432

    const size_t xT_batch = (size_t)N * 64 * 2;            // bf16 bytes per batch
    const size_t part_b   = (size_t)B * nblk * 4224 * 4;
    const size_t p2_b     = (size_t)B * 16 * 4224 * 4;
    const size_t wf_b     = (size_t)B * 4096 * 2;
    const bool   full     = ws_size >= (size_t)B * xT_batch + part_b + p2_b + wf_b;

    unsigned short* xT    = (unsigned short*)d_ws;
    char* p               = (char*)d_ws + (full ? B * xT_batch : xT_batch);
    float* part           = (float*)p;
    float* part2          = part + (size_t)B * nblk * 4224;
    unsigned short* wf_bf = (unsigned short*)(part2 + (size_t)B * 16 * 4224);

    if (full) {
        kv_ctx_fused<<<dim3(nblk, B), 256, 0, stream>>>(x, w_qkv, xT, part, N, nblk, 0);
        reduce_kernel<<<dim3(17, 16, B), 256, 0, stream>>>(part, part2, nblk);
        finalize_kernel<<<dim3(8, B), 256, 0, stream>>>(part2, w_qkv, w_out, wf_bf);
        out_gemm_mfma<<<dim3(nblk, B), 256, 0, stream>>>(xT, wf_bf, b_out, y, N, 0);
    } else {
        for (int b = 0; b < B; ++b)
            kv_ctx_fused<<<dim3(nblk, 1), 256, 0, stream>>>(x, w_qkv, xT, part, N, nblk, b);
        reduce_kernel<<<dim3(17, 16, B), 256, 0, stream>>>(part, part2, nblk);
        finalize_kernel<<<dim3(8, B), 256, 0, stream>>>(part2, w_qkv, w_out, wf_bf);
        for (int b = 0; b < B; ++b) {
            transpose_kernel<<<dim3(N / 64, 1), 256, 0, stream>>>(x, xT, N, b);
            out_gemm_mfma<<<dim3(nblk, 1), 256, 0, stream>>>(xT, wf_bf, b_out, y, N, b);
        }
    }
}